// Round 6
// baseline (109.648 us; speedup 1.0000x reference)
//
#include <hip/hip_runtime.h>
#include <hip/hip_bf16.h>

#define B_TOTAL 65536
#define NR 4
#define VD 100
#define HD 200
#define DK 32
#define MH 128
#define RD 64

typedef __attribute__((ext_vector_type(8))) short bf16x8;
typedef __attribute__((ext_vector_type(4))) float f32x4;

static __device__ inline unsigned short f2bf(float x) {
    __hip_bfloat16 h = __float2bfloat16(x);
    return __builtin_bit_cast(unsigned short, h);
}

// ---- workspace layout (bytes) ---- total 953,344 B (< 1.02 MB proven in R1)
#define WS_GD    0         // 2400 * 8 = 19200
#define WS_CNT   19200     // 16
#define WS_LIST  19456     // 4 * 65536 * 2 = 524288 (ushort b per bucket slot)
#define WS_VB    543744    // 65536 bytes (v bit per element)
#define WS_W1F   609280    // 114688 * 2 = 229376
#define WS_W2F   838656    // 57344 * 2 = 114688

// ---------------- kernel 0a: precompute G (fp64) + zero counters ----------------
__global__ __launch_bounds__(256) void k0_prep(
    const float* __restrict__ rule_emb, const float* __restrict__ Wq,
    const float* __restrict__ bq, const float* __restrict__ Wk,
    double* __restrict__ Gd, int* __restrict__ cnt)
{
    int tid = threadIdx.x;
    if (tid < NR) cnt[tid] = 0;

    __shared__ double readS[NR * DK];
    if (tid < NR * DK) {
        int r = tid >> 5, k = tid & 31;
        double a = (double)bq[k];
        for (int d = 0; d < RD; ++d)
            a += (double)rule_emb[r * RD + d] * (double)Wq[d * DK + k];
        readS[tid] = a;
    }
    __syncthreads();

    for (int idx = tid; idx < 300 * 8; idx += 256) {
        int j = idx >> 3, p = idx & 7;
        int r = p >> 1, v = p & 1;
        int s = j / 100, dd = j - s * 100;
        double g = 0.0;
        if (s == v) {
            for (int k = 0; k < DK; ++k)
                g += (double)Wk[(v * HD + dd) * DK + k] * readS[r * DK + k];
        } else if (s == 2) {
            for (int k = 0; k < DK; ++k)
                g += (double)Wk[(v * HD + 100 + dd) * DK + k] * readS[r * DK + k];
        }
        Gd[idx] = g;  // layout Gd[j*8 + p]
    }
}

// ---------------- kernel 0b: W1/W2 -> bf16 MFMA B-fragment layout ----------------
// W1f elem (r,ks,n,l,j) at ((r*7+ks)*8+n)*512 + l*8 + j ; value W1[r][k][c],
//   k = ks*32 + (l>>4)*8 + j (0 if k>=200), c = n*16 + (l&15)
// W2f elem (r,ks,n,l,j) at ((r*4+ks)*7+n)*512 + l*8 + j ; value W2[r][k][c],
//   k = ks*32 + (l>>4)*8 + j, c = n*16 + (l&15) (0 if c>=100)
__global__ __launch_bounds__(256) void k0_wfrag(
    const float* __restrict__ W1, const float* __restrict__ W2,
    unsigned short* __restrict__ W1f, unsigned short* __restrict__ W2f)
{
    int i = blockIdx.x * 256 + threadIdx.x;
    if (i < 114688) {
        int r = i / 28672, rem = i % 28672;
        int ks = rem / 4096, rem2 = rem % 4096;
        int n = rem2 >> 9, l = (rem2 >> 3) & 63, j = rem2 & 7;
        int k = ks * 32 + ((l >> 4) << 3) + j;
        int c = n * 16 + (l & 15);
        float v = (k < HD) ? W1[((size_t)r * HD + k) * MH + c] : 0.f;
        W1f[i] = f2bf(v);
    } else if (i < 114688 + 57344) {
        int t = i - 114688;
        int r = t / 14336, rem = t % 14336;
        int ks = rem / 3584, rem2 = rem % 3584;
        int n = rem2 >> 9, l = (rem2 >> 3) & 63, j = rem2 & 7;
        int k = ks * 32 + ((l >> 4) << 3) + j;
        int c = n * 16 + (l & 15);
        float v = (c < VD) ? W2[((size_t)r * MH + k) * VD + c] : 0.f;
        W2f[t] = f2bf(v);
    }
}

// ---------------- kernel 1: selection (fp64) + bucket compaction ----------------
// v2: K-split across 4 wave-quarters. Block = 1024 threads = 256 elements x
// 4 j-quarters (chunk ranges [19w, min(19w+19,75))). Raises occupancy from
// 4 waves/CU (R5 counters: VALUBusy 7%, Occupancy 10.5% -- latency-starved)
// to 16 waves/CU. fp64 partials -> LDS -> quarter-0 reduces + identical
// argmax/atomic bucket logic as the proven R5 version.
__global__ __launch_bounds__(1024) void k1_select(
    const float* __restrict__ hidden, const double* __restrict__ Gd,
    int* __restrict__ cnt, unsigned short* __restrict__ list16,
    unsigned char* __restrict__ vbyte)
{
    __shared__ double Gs[300 * 8];        // 19200 B, broadcast reads (uniform addr)
    __shared__ double pacc[3][256][8];    // 49152 B partials for quarters 1..3
    __shared__ int lcnt[NR];
    __shared__ int lbase[NR];
    int tid = threadIdx.x;
    for (int i = tid; i < 300 * 8; i += 1024) Gs[i] = Gd[i];
    if (tid < NR) lcnt[tid] = 0;
    __syncthreads();

    int w4 = tid >> 8;      // j-quarter 0..3
    int e  = tid & 255;     // element within block
    int b  = blockIdx.x * 256 + e;
    const float4* h4 = (const float4*)(hidden + (size_t)b * 300);

    double acc[8];
#pragma unroll
    for (int p = 0; p < 8; ++p) acc[p] = 0.0;

    int c0 = w4 * 19;
    int c1 = c0 + 19; if (c1 > 75) c1 = 75;   // quarters: 19,19,19,18 chunks
    for (int c = c0; c < c1; ++c) {
        float4 hv = h4[c];
        float he[4] = {hv.x, hv.y, hv.z, hv.w};
        int j = c * 4;
#pragma unroll
        for (int q = 0; q < 4; ++q) {
            double x = (double)he[q];
#pragma unroll
            for (int p = 0; p < 8; ++p) acc[p] += x * Gs[(j + q) * 8 + p];
        }
    }

    if (w4 > 0) {
#pragma unroll
        for (int p = 0; p < 8; ++p) pacc[w4 - 1][e][p] = acc[p];
    }
    __syncthreads();

    int r = 0, v = 0, pos = 0;
    if (w4 == 0) {
#pragma unroll
        for (int q = 0; q < 3; ++q)
#pragma unroll
            for (int p = 0; p < 8; ++p) acc[p] += pacc[q][e][p];

        // first-occurrence argmax (matches jnp.argmax)
        int best = 0; double bv = acc[0];
#pragma unroll
        for (int p = 1; p < 8; ++p) if (acc[p] > bv) { bv = acc[p]; best = p; }
        r = best >> 1; v = best & 1;

        vbyte[b] = (unsigned char)v;
        pos = atomicAdd(&lcnt[r], 1);
    }
    __syncthreads();
    if (tid < NR) lbase[tid] = atomicAdd(&cnt[tid], lcnt[tid]);
    __syncthreads();
    if (w4 == 0) list16[r * B_TOTAL + lbase[r] + pos] = (unsigned short)b;
}

// ---------------- kernel 2: bucketed bf16-MFMA MLP ----------------
// 256 threads = 4 waves; block covers 128 rows of one rule bucket.
// Wave w owns rows w*32..w*32+31 (2 M-tiles of 16).
// GEMM1: C1 = relu(X @ W1[r])  X:128x224(bf16, k 200..231 zeroed) W1:224x128
// GEMM2: out = C1 @ W2[r]      C1:128x128(bf16) W2:128x112(pad cols>=100)
__global__ __launch_bounds__(256) void k2_mlp(
    const float* __restrict__ hidden,
    const unsigned short* __restrict__ W1f, const unsigned short* __restrict__ W2f,
    const int* __restrict__ cnt, const unsigned short* __restrict__ list16,
    const unsigned char* __restrict__ vbyte, float* __restrict__ out)
{
    int r = blockIdx.y;
    int nb = cnt[r];
    int m0 = blockIdx.x * 128;
    if (m0 >= nb) return;
    int me = nb - m0; if (me > 128) me = 128;

    __shared__ __align__(16) unsigned short shbuf[128 * 232]; // X: [128][232] ; later C1: [128][136]
    __shared__ int ent[128];

    int tid = threadIdx.x;
    int wave = tid >> 6, lane = tid & 63;
    int lr = lane & 15, lk = lane >> 4;
    int wrow0 = wave * 32;

    if (tid < 128) {
        int idx = m0 + tid; if (idx > nb - 1) idx = nb - 1;
        int b = list16[r * B_TOTAL + idx];
        int v = vbyte[b];
        ent[tid] = (b << 1) | v;
    }
    __syncthreads();

    // stage X (bf16): row e, 50 float4-chunks of rule_mlp_input -> covers k [0,200)
    for (int i = tid; i < 128 * 50; i += 256) {
        int e = i / 50, q = i - e * 50;
        int en = ent[e];
        int b = en >> 1, v = en & 1;
        int seg = (q < 25) ? v : (1 - v);
        int q25 = (q < 25) ? q : q - 25;
        float4 val = *(const float4*)(hidden + (size_t)b * 300 + seg * 100 + q25 * 4);
        ushort4 o;
        o.x = f2bf(val.x); o.y = f2bf(val.y); o.z = f2bf(val.z); o.w = f2bf(val.w);
        *(ushort4*)&shbuf[e * 232 + q * 4] = o;
    }
    // zero-pad k = [200,232) COMPLETELY: 4 bf16x8 chunks/row at 200,208,216,224.
    // (GEMM1 ks=6 reads k in [192,224): any stale LDS NaN * 0-weight = NaN
    //  poisons the C1 row, relu launders NaN->0 -> zeroed output rows.)
    for (int i = tid; i < 128 * 4; i += 256) {
        int row = i >> 2, part = i & 3;
        bf16x8 z = {0, 0, 0, 0, 0, 0, 0, 0};
        *(bf16x8*)&shbuf[row * 232 + 200 + part * 8] = z;
    }
    __syncthreads();

    // ---- GEMM1 ----
    const unsigned short* W1f_r = W1f + (size_t)r * 28672;
    f32x4 acc1[2][8];
#pragma unroll
    for (int mt = 0; mt < 2; ++mt)
#pragma unroll
        for (int n = 0; n < 8; ++n) acc1[mt][n] = (f32x4){0.f, 0.f, 0.f, 0.f};

#pragma unroll
    for (int ks = 0; ks < 7; ++ks) {
        bf16x8 a0 = *(const bf16x8*)&shbuf[(wrow0 + lr) * 232 + ks * 32 + lk * 8];
        bf16x8 a1 = *(const bf16x8*)&shbuf[(wrow0 + 16 + lr) * 232 + ks * 32 + lk * 8];
#pragma unroll
        for (int n = 0; n < 8; ++n) {
            bf16x8 bfr = *(const bf16x8*)&W1f_r[(size_t)(ks * 8 + n) * 512 + lane * 8];
            acc1[0][n] = __builtin_amdgcn_mfma_f32_16x16x32_bf16(a0, bfr, acc1[0][n], 0, 0, 0);
            acc1[1][n] = __builtin_amdgcn_mfma_f32_16x16x32_bf16(a1, bfr, acc1[1][n], 0, 0, 0);
        }
    }

    __syncthreads();  // all waves done reading X before overlay

    // relu -> bf16 -> C1 transpose-store via C-layout: row=(lane>>4)*4+j, col=n*16+(lane&15)
#pragma unroll
    for (int mt = 0; mt < 2; ++mt)
#pragma unroll
        for (int n = 0; n < 8; ++n)
#pragma unroll
            for (int j = 0; j < 4; ++j) {
                float v = fmaxf(acc1[mt][n][j], 0.f);
                int row = wrow0 + mt * 16 + lk * 4 + j;
                shbuf[row * 136 + n * 16 + lr] = f2bf(v);
            }
    __syncthreads();

    // ---- GEMM2 ----
    const unsigned short* W2f_r = W2f + (size_t)r * 14336;
    f32x4 acc2[2][7];
#pragma unroll
    for (int mt = 0; mt < 2; ++mt)
#pragma unroll
        for (int n = 0; n < 7; ++n) acc2[mt][n] = (f32x4){0.f, 0.f, 0.f, 0.f};

#pragma unroll
    for (int ks = 0; ks < 4; ++ks) {
        bf16x8 a0 = *(const bf16x8*)&shbuf[(wrow0 + lr) * 136 + ks * 32 + lk * 8];
        bf16x8 a1 = *(const bf16x8*)&shbuf[(wrow0 + 16 + lr) * 136 + ks * 32 + lk * 8];
#pragma unroll
        for (int n = 0; n < 7; ++n) {
            bf16x8 bfr = *(const bf16x8*)&W2f_r[(size_t)(ks * 7 + n) * 512 + lane * 8];
            acc2[0][n] = __builtin_amdgcn_mfma_f32_16x16x32_bf16(a0, bfr, acc2[0][n], 0, 0, 0);
            acc2[1][n] = __builtin_amdgcn_mfma_f32_16x16x32_bf16(a1, bfr, acc2[1][n], 0, 0, 0);
        }
    }

    // scatter-store
#pragma unroll
    for (int mt = 0; mt < 2; ++mt)
#pragma unroll
        for (int n = 0; n < 7; ++n) {
            int col = n * 16 + lr;
            if (col < VD) {
#pragma unroll
                for (int j = 0; j < 4; ++j) {
                    int e = wrow0 + mt * 16 + lk * 4 + j;
                    if (e < me) {
                        int b = ent[e] >> 1;
                        out[(size_t)b * VD + col] = acc2[mt][n][j];
                    }
                }
            }
        }
}

extern "C" void kernel_launch(void* const* d_in, const int* in_sizes, int n_in,
                              void* d_out, int out_size, void* d_ws, size_t ws_size,
                              hipStream_t stream) {
    (void)in_sizes; (void)n_in; (void)out_size; (void)ws_size;
    const float* hidden   = (const float*)d_in[0];
    const float* rule_emb = (const float*)d_in[1];
    const float* Wq       = (const float*)d_in[2];
    const float* bq       = (const float*)d_in[3];
    const float* Wk       = (const float*)d_in[4];
    const float* W1       = (const float*)d_in[5];
    const float* W2       = (const float*)d_in[6];
    float* out = (float*)d_out;

    char* ws = (char*)d_ws;
    double* Gd            = (double*)(ws + WS_GD);
    int* cnt              = (int*)(ws + WS_CNT);
    unsigned short* list16 = (unsigned short*)(ws + WS_LIST);
    unsigned char* vbyte  = (unsigned char*)(ws + WS_VB);
    unsigned short* W1f   = (unsigned short*)(ws + WS_W1F);
    unsigned short* W2f   = (unsigned short*)(ws + WS_W2F);

    k0_prep<<<1, 256, 0, stream>>>(rule_emb, Wq, bq, Wk, Gd, cnt);
    k0_wfrag<<<672, 256, 0, stream>>>(W1, W2, W1f, W2f);
    k1_select<<<256, 1024, 0, stream>>>(hidden, Gd, cnt, list16, vbyte);
    k2_mlp<<<dim3(512, NR), 256, 0, stream>>>(hidden, W1f, W2f, cnt, list16, vbyte, out);
}

// Round 7
// 95.687 us; speedup vs baseline: 1.1459x; 1.1459x over previous
//
#include <hip/hip_runtime.h>
#include <hip/hip_bf16.h>

#define B_TOTAL 65536
#define NR 4
#define VD 100
#define HD 200
#define DK 32
#define MH 128
#define RD 64

typedef __attribute__((ext_vector_type(8))) short bf16x8;
typedef __attribute__((ext_vector_type(4))) float f32x4;

static __device__ inline unsigned short f2bf(float x) {
    __hip_bfloat16 h = __float2bfloat16(x);
    return __builtin_bit_cast(unsigned short, h);
}

// ---- workspace layout (bytes) ---- total 953,344 B (< 1.02 MB proven in R1)
#define WS_GD    0         // 2400 * 8 = 19200
#define WS_CNT   19200     // 16
#define WS_LIST  19456     // 4 * 65536 * 2 = 524288 (ushort b per bucket slot)
#define WS_VB    543744    // 65536 bytes (v bit per element)
#define WS_W1F   609280    // 114688 * 2 = 229376
#define WS_W2F   838656    // 57344 * 2 = 114688

// ---------------- kernel 0a: precompute G (fp64) + zero counters ----------------
__global__ __launch_bounds__(256) void k0_prep(
    const float* __restrict__ rule_emb, const float* __restrict__ Wq,
    const float* __restrict__ bq, const float* __restrict__ Wk,
    double* __restrict__ Gd, int* __restrict__ cnt)
{
    int tid = threadIdx.x;
    if (tid < NR) cnt[tid] = 0;

    __shared__ double readS[NR * DK];
    if (tid < NR * DK) {
        int r = tid >> 5, k = tid & 31;
        double a = (double)bq[k];
        for (int d = 0; d < RD; ++d)
            a += (double)rule_emb[r * RD + d] * (double)Wq[d * DK + k];
        readS[tid] = a;
    }
    __syncthreads();

    for (int idx = tid; idx < 300 * 8; idx += 256) {
        int j = idx >> 3, p = idx & 7;
        int r = p >> 1, v = p & 1;
        int s = j / 100, dd = j - s * 100;
        double g = 0.0;
        if (s == v) {
            for (int k = 0; k < DK; ++k)
                g += (double)Wk[(v * HD + dd) * DK + k] * readS[r * DK + k];
        } else if (s == 2) {
            for (int k = 0; k < DK; ++k)
                g += (double)Wk[(v * HD + 100 + dd) * DK + k] * readS[r * DK + k];
        }
        Gd[idx] = g;  // layout Gd[j*8 + p]
    }
}

// ---------------- kernel 0b: W1/W2 -> bf16 MFMA B-fragment layout ----------------
// W1f elem (r,ks,n,l,j) at ((r*7+ks)*8+n)*512 + l*8 + j ; value W1[r][k][c],
//   k = ks*32 + (l>>4)*8 + j (0 if k>=200), c = n*16 + (l&15)
// W2f elem (r,ks,n,l,j) at ((r*4+ks)*7+n)*512 + l*8 + j ; value W2[r][k][c],
//   k = ks*32 + (l>>4)*8 + j, c = n*16 + (l&15) (0 if c>=100)
__global__ __launch_bounds__(256) void k0_wfrag(
    const float* __restrict__ W1, const float* __restrict__ W2,
    unsigned short* __restrict__ W1f, unsigned short* __restrict__ W2f)
{
    int i = blockIdx.x * 256 + threadIdx.x;
    if (i < 114688) {
        int r = i / 28672, rem = i % 28672;
        int ks = rem / 4096, rem2 = rem % 4096;
        int n = rem2 >> 9, l = (rem2 >> 3) & 63, j = rem2 & 7;
        int k = ks * 32 + ((l >> 4) << 3) + j;
        int c = n * 16 + (l & 15);
        float v = (k < HD) ? W1[((size_t)r * HD + k) * MH + c] : 0.f;
        W1f[i] = f2bf(v);
    } else if (i < 114688 + 57344) {
        int t = i - 114688;
        int r = t / 14336, rem = t % 14336;
        int ks = rem / 3584, rem2 = rem % 3584;
        int n = rem2 >> 9, l = (rem2 >> 3) & 63, j = rem2 & 7;
        int k = ks * 32 + ((l >> 4) << 3) + j;
        int c = n * 16 + (l & 15);
        float v = (c < VD) ? W2[((size_t)r * MH + k) * VD + c] : 0.f;
        W2f[t] = f2bf(v);
    }
}

// ---------------- kernel 1: selection (fp64) + bucket compaction ----------------
// v3: back to R5's proven 1-thread-1-element contiguous row walk (best L1
// behavior, FETCH 42MB), with the two latency sources removed:
//  (a) 15-deep load batching -> 15 outstanding VMEM hide ~900cyc HBM latency
//      (R5 had ~2 in flight; R6's K-split fixed occupancy but blew L1 reuse,
//       FETCH 42->150MB, net neutral).
//  (b) G read with WAVE-UNIFORM index straight from global -> compiler
//      scalarizes to s_load_dwordx16 (K$, scalar pipe, no per-lane LDS ops;
//      R5 spent ~2400 ds_read_b64/thread on the G table -> ds-pipe bound).
// Summation order identical to R5 -> same fp64 bits -> same argmax (proven).
__global__ __launch_bounds__(256) void k1_select(
    const float* __restrict__ hidden, const double* __restrict__ Gd,
    int* __restrict__ cnt, unsigned short* __restrict__ list16,
    unsigned char* __restrict__ vbyte)
{
    __shared__ int lcnt[NR];
    __shared__ int lbase[NR];
    int tid = threadIdx.x;
    if (tid < NR) lcnt[tid] = 0;
    __syncthreads();

    int b = blockIdx.x * 256 + tid;
    const float4* h4 = (const float4*)(hidden + (size_t)b * 300);

    double acc[8];
#pragma unroll
    for (int p = 0; p < 8; ++p) acc[p] = 0.0;

    for (int c0 = 0; c0 < 75; c0 += 15) {
        float4 hv[15];
#pragma unroll
        for (int u = 0; u < 15; ++u) hv[u] = h4[c0 + u];
#pragma unroll
        for (int u = 0; u < 15; ++u) {
            float he[4] = {hv[u].x, hv[u].y, hv[u].z, hv[u].w};
            int j = (c0 + u) * 4;
#pragma unroll
            for (int q = 0; q < 4; ++q) {
                double x = (double)he[q];
                const double* g = Gd + (size_t)(j + q) * 8;   // wave-uniform addr
#pragma unroll
                for (int p = 0; p < 8; ++p) acc[p] = fma(x, g[p], acc[p]);
            }
        }
    }

    // first-occurrence argmax (matches jnp.argmax)
    int best = 0; double bv = acc[0];
#pragma unroll
    for (int p = 1; p < 8; ++p) if (acc[p] > bv) { bv = acc[p]; best = p; }
    int r = best >> 1, v = best & 1;

    vbyte[b] = (unsigned char)v;
    int pos = atomicAdd(&lcnt[r], 1);
    __syncthreads();
    if (tid < NR) lbase[tid] = atomicAdd(&cnt[tid], lcnt[tid]);
    __syncthreads();
    list16[r * B_TOTAL + lbase[r] + pos] = (unsigned short)b;
}

// ---------------- kernel 2: bucketed bf16-MFMA MLP ----------------
// 256 threads = 4 waves; block covers 128 rows of one rule bucket.
// Wave w owns rows w*32..w*32+31 (2 M-tiles of 16).
// GEMM1: C1 = relu(X @ W1[r])  X:128x224(bf16, k 200..231 zeroed) W1:224x128
// GEMM2: out = C1 @ W2[r]      C1:128x128(bf16) W2:128x112(pad cols>=100)
__global__ __launch_bounds__(256) void k2_mlp(
    const float* __restrict__ hidden,
    const unsigned short* __restrict__ W1f, const unsigned short* __restrict__ W2f,
    const int* __restrict__ cnt, const unsigned short* __restrict__ list16,
    const unsigned char* __restrict__ vbyte, float* __restrict__ out)
{
    int r = blockIdx.y;
    int nb = cnt[r];
    int m0 = blockIdx.x * 128;
    if (m0 >= nb) return;
    int me = nb - m0; if (me > 128) me = 128;

    __shared__ __align__(16) unsigned short shbuf[128 * 232]; // X: [128][232] ; later C1: [128][136]
    __shared__ int ent[128];

    int tid = threadIdx.x;
    int wave = tid >> 6, lane = tid & 63;
    int lr = lane & 15, lk = lane >> 4;
    int wrow0 = wave * 32;

    if (tid < 128) {
        int idx = m0 + tid; if (idx > nb - 1) idx = nb - 1;
        int b = list16[r * B_TOTAL + idx];
        int v = vbyte[b];
        ent[tid] = (b << 1) | v;
    }
    __syncthreads();

    // stage X (bf16): row e, 50 float4-chunks of rule_mlp_input -> covers k [0,200)
    for (int i = tid; i < 128 * 50; i += 256) {
        int e = i / 50, q = i - e * 50;
        int en = ent[e];
        int b = en >> 1, v = en & 1;
        int seg = (q < 25) ? v : (1 - v);
        int q25 = (q < 25) ? q : q - 25;
        float4 val = *(const float4*)(hidden + (size_t)b * 300 + seg * 100 + q25 * 4);
        ushort4 o;
        o.x = f2bf(val.x); o.y = f2bf(val.y); o.z = f2bf(val.z); o.w = f2bf(val.w);
        *(ushort4*)&shbuf[e * 232 + q * 4] = o;
    }
    // zero-pad k = [200,232) COMPLETELY: 4 bf16x8 chunks/row at 200,208,216,224.
    // (GEMM1 ks=6 reads k in [192,224): any stale LDS NaN * 0-weight = NaN
    //  poisons the C1 row, relu launders NaN->0 -> zeroed output rows.)
    for (int i = tid; i < 128 * 4; i += 256) {
        int row = i >> 2, part = i & 3;
        bf16x8 z = {0, 0, 0, 0, 0, 0, 0, 0};
        *(bf16x8*)&shbuf[row * 232 + 200 + part * 8] = z;
    }
    __syncthreads();

    // ---- GEMM1 ----
    const unsigned short* W1f_r = W1f + (size_t)r * 28672;
    f32x4 acc1[2][8];
#pragma unroll
    for (int mt = 0; mt < 2; ++mt)
#pragma unroll
        for (int n = 0; n < 8; ++n) acc1[mt][n] = (f32x4){0.f, 0.f, 0.f, 0.f};

#pragma unroll
    for (int ks = 0; ks < 7; ++ks) {
        bf16x8 a0 = *(const bf16x8*)&shbuf[(wrow0 + lr) * 232 + ks * 32 + lk * 8];
        bf16x8 a1 = *(const bf16x8*)&shbuf[(wrow0 + 16 + lr) * 232 + ks * 32 + lk * 8];
#pragma unroll
        for (int n = 0; n < 8; ++n) {
            bf16x8 bfr = *(const bf16x8*)&W1f_r[(size_t)(ks * 8 + n) * 512 + lane * 8];
            acc1[0][n] = __builtin_amdgcn_mfma_f32_16x16x32_bf16(a0, bfr, acc1[0][n], 0, 0, 0);
            acc1[1][n] = __builtin_amdgcn_mfma_f32_16x16x32_bf16(a1, bfr, acc1[1][n], 0, 0, 0);
        }
    }

    __syncthreads();  // all waves done reading X before overlay

    // relu -> bf16 -> C1 transpose-store via C-layout: row=(lane>>4)*4+j, col=n*16+(lane&15)
#pragma unroll
    for (int mt = 0; mt < 2; ++mt)
#pragma unroll
        for (int n = 0; n < 8; ++n)
#pragma unroll
            for (int j = 0; j < 4; ++j) {
                float v = fmaxf(acc1[mt][n][j], 0.f);
                int row = wrow0 + mt * 16 + lk * 4 + j;
                shbuf[row * 136 + n * 16 + lr] = f2bf(v);
            }
    __syncthreads();

    // ---- GEMM2 ----
    const unsigned short* W2f_r = W2f + (size_t)r * 14336;
    f32x4 acc2[2][7];
#pragma unroll
    for (int mt = 0; mt < 2; ++mt)
#pragma unroll
        for (int n = 0; n < 7; ++n) acc2[mt][n] = (f32x4){0.f, 0.f, 0.f, 0.f};

#pragma unroll
    for (int ks = 0; ks < 4; ++ks) {
        bf16x8 a0 = *(const bf16x8*)&shbuf[(wrow0 + lr) * 136 + ks * 32 + lk * 8];
        bf16x8 a1 = *(const bf16x8*)&shbuf[(wrow0 + 16 + lr) * 136 + ks * 32 + lk * 8];
#pragma unroll
        for (int n = 0; n < 7; ++n) {
            bf16x8 bfr = *(const bf16x8*)&W2f_r[(size_t)(ks * 7 + n) * 512 + lane * 8];
            acc2[0][n] = __builtin_amdgcn_mfma_f32_16x16x32_bf16(a0, bfr, acc2[0][n], 0, 0, 0);
            acc2[1][n] = __builtin_amdgcn_mfma_f32_16x16x32_bf16(a1, bfr, acc2[1][n], 0, 0, 0);
        }
    }

    // scatter-store
#pragma unroll
    for (int mt = 0; mt < 2; ++mt)
#pragma unroll
        for (int n = 0; n < 7; ++n) {
            int col = n * 16 + lr;
            if (col < VD) {
#pragma unroll
                for (int j = 0; j < 4; ++j) {
                    int e = wrow0 + mt * 16 + lk * 4 + j;
                    if (e < me) {
                        int b = ent[e] >> 1;
                        out[(size_t)b * VD + col] = acc2[mt][n][j];
                    }
                }
            }
        }
}

extern "C" void kernel_launch(void* const* d_in, const int* in_sizes, int n_in,
                              void* d_out, int out_size, void* d_ws, size_t ws_size,
                              hipStream_t stream) {
    (void)in_sizes; (void)n_in; (void)out_size; (void)ws_size;
    const float* hidden   = (const float*)d_in[0];
    const float* rule_emb = (const float*)d_in[1];
    const float* Wq       = (const float*)d_in[2];
    const float* bq       = (const float*)d_in[3];
    const float* Wk       = (const float*)d_in[4];
    const float* W1       = (const float*)d_in[5];
    const float* W2       = (const float*)d_in[6];
    float* out = (float*)d_out;

    char* ws = (char*)d_ws;
    double* Gd            = (double*)(ws + WS_GD);
    int* cnt              = (int*)(ws + WS_CNT);
    unsigned short* list16 = (unsigned short*)(ws + WS_LIST);
    unsigned char* vbyte  = (unsigned char*)(ws + WS_VB);
    unsigned short* W1f   = (unsigned short*)(ws + WS_W1F);
    unsigned short* W2f   = (unsigned short*)(ws + WS_W2F);

    k0_prep<<<1, 256, 0, stream>>>(rule_emb, Wq, bq, Wk, Gd, cnt);
    k0_wfrag<<<672, 256, 0, stream>>>(W1, W2, W1f, W2f);
    k1_select<<<256, 256, 0, stream>>>(hidden, Gd, cnt, list16, vbyte);
    k2_mlp<<<dim3(512, NR), 256, 0, stream>>>(hidden, W1f, W2f, cnt, list16, vbyte, out);
}